// Round 1
// baseline (90.331 us; speedup 1.0000x reference)
//
#include <hip/hip_runtime.h>
#include <hip/hip_bf16.h>

// Reference collapses: only outputs[-1] is returned, and since T (2048) >= STEPS (128),
// the final sliding window is exactly x[:, T-128 : T]. h0 is dead.
// out[b] = sum(softmax(scale * w) * w) with w = x[b, 1920:2048].

#define BATCH 8192
#define T_DIM 2048
#define STEPS 128

__global__ __launch_bounds__(256) void TemporalOperator_87806311400070_kernel(
    const float* __restrict__ x, const int* __restrict__ scale_ptr,
    float* __restrict__ out)
{
    const float scale = (float)(*scale_ptr);

    // one wave (64 lanes) per row; 256-thread block = 4 rows
    const int lane = threadIdx.x & 63;
    const int wave = threadIdx.x >> 6;
    const int row  = blockIdx.x * 4 + wave;
    if (row >= BATCH) return;

    const float* xr = x + (size_t)row * T_DIM + (T_DIM - STEPS);
    const float2 v = *(const float2*)(xr + lane * 2);

    // wave-wide max
    float m = fmaxf(v.x, v.y);
    #pragma unroll
    for (int off = 32; off >= 1; off >>= 1)
        m = fmaxf(m, __shfl_down(m, off));
    m = __shfl(m, 0);

    const float e0 = expf(scale * (v.x - m));
    const float e1 = expf(scale * (v.y - m));
    float num = e0 * v.x + e1 * v.y;
    float den = e0 + e1;

    #pragma unroll
    for (int off = 32; off >= 1; off >>= 1) {
        num += __shfl_down(num, off);
        den += __shfl_down(den, off);
    }

    if (lane == 0) out[row] = num / den;
}

extern "C" void kernel_launch(void* const* d_in, const int* in_sizes, int n_in,
                              void* d_out, int out_size, void* d_ws, size_t ws_size,
                              hipStream_t stream) {
    const float* x     = (const float*)d_in[0];
    // d_in[1] = h0 — dead (window fully refilled by t = T-1)
    const int*   scale = (const int*)d_in[2];
    float*       out   = (float*)d_out;

    const int rows_per_block = 4;                    // 256 threads = 4 waves
    const int grid = (BATCH + rows_per_block - 1) / rows_per_block;
    TemporalOperator_87806311400070_kernel<<<grid, 256, 0, stream>>>(x, scale, out);
}